// Round 12
// baseline (1391.425 us; speedup 1.0000x reference)
//
#include <hip/hip_runtime.h>
#include <hip/hip_bf16.h>
#include <cstdint>
#include <math.h>

#define N_TOK 8192
#define D_DIM 1024
#define F_DIM 4096
#define NE 8
#define CAP 8192
#define MAXT 72    // max sum_e ceil(cnt_e/256) = 71, padded

typedef __attribute__((ext_vector_type(8))) short short8;
typedef __attribute__((ext_vector_type(4))) short short4v;
typedef __attribute__((ext_vector_type(4))) float f32x4;

__device__ __forceinline__ short f2bf(float f) {
  __bf16 b = (__bf16)f;
  return *(short*)&b;
}
__device__ __forceinline__ float bf2f(short u) {
  union { unsigned int i; float f; } c;
  c.i = ((unsigned int)(unsigned short)u) << 16;
  return c.f;
}
__device__ __forceinline__ void gload(const void* g, void* l) {
  __builtin_amdgcn_global_load_lds(
      (const __attribute__((address_space(1))) uint32_t*)g,
      (__attribute__((address_space(3))) uint32_t*)l, 16, 0, 0);
}

// LDS tile geometry (BK=32): row = 64 B (4 chunks of 16 B). Swizzle: chunk
// ch stored at ch ^ f(r), f(r) = (r>>1)&3. Read af/bfr at (row, lhi^f(row)):
// bank tally over a wave = exactly 2 lanes per bank (free, m136).

// ---------------- gating + fused X->bf16 ------------------------------------
__global__ __launch_bounds__(256) void gate_kernel(
    const float* __restrict__ X, const float* __restrict__ Wg,
    const float* __restrict__ bg, int* __restrict__ cnt,
    int* __restrict__ bucket, float* __restrict__ pairw,
    unsigned short* __restrict__ Xb)
{
  const int token = blockIdx.x;
  const int tid = threadIdx.x;
  const float4* x4 = (const float4*)(X + (size_t)token * D_DIM);
  const float4* wg4 = (const float4*)Wg;
  float part[NE];
#pragma unroll
  for (int e = 0; e < NE; ++e) part[e] = 0.f;
  const float4 xv = x4[tid];
#pragma unroll
  for (int e = 0; e < NE; ++e) {
    const float4 wv = wg4[e * (D_DIM / 4) + tid];
    part[e] = fmaf(xv.x, wv.x, fmaf(xv.y, wv.y, fmaf(xv.z, wv.z, fmaf(xv.w, wv.w, part[e]))));
  }
  short4v o;
  o.x = f2bf(xv.x); o.y = f2bf(xv.y); o.z = f2bf(xv.z); o.w = f2bf(xv.w);
  ((short4v*)(Xb + (size_t)token * D_DIM))[tid] = o;

#pragma unroll
  for (int e = 0; e < NE; ++e) {
#pragma unroll
    for (int off = 32; off > 0; off >>= 1) part[e] += __shfl_down(part[e], off);
  }
  __shared__ float wsum[4][NE];
  const int wave = tid >> 6;
  if ((tid & 63) == 0) {
#pragma unroll
    for (int e = 0; e < NE; ++e) wsum[wave][e] = part[e];
  }
  __syncthreads();
  if (tid == 0) {
    float lg[NE];
#pragma unroll
    for (int e = 0; e < NE; ++e)
      lg[e] = wsum[0][e] + wsum[1][e] + wsum[2][e] + wsum[3][e] + bg[e];
    int e0 = 0;
#pragma unroll
    for (int e = 1; e < NE; ++e) if (lg[e] > lg[e0]) e0 = e;     // jax tie-break: lower idx
    int e1 = (e0 == 0) ? 1 : 0;
#pragma unroll
    for (int e = 0; e < NE; ++e) if (e != e0 && lg[e] > lg[e1]) e1 = e;
    float p1 = expf(lg[e1] - lg[e0]);            // p0 = 1; softmax denom cancels
    float inv = 1.f / (1.f + p1);
    pairw[token * 2]     = inv;
    pairw[token * 2 + 1] = p1 * inv;
    int pos0 = atomicAdd(&cnt[e0], 1);
    bucket[e0 * CAP + pos0] = token * 2;
    int pos1 = atomicAdd(&cnt[e1], 1);
    bucket[e1 * CAP + pos1] = token * 2 + 1;
  }
}

// ---------------- prefix sums (row offsets + 256-row tile offsets) ----------
__global__ void prefix_kernel(const int* __restrict__ cnt,
                              int* __restrict__ expoff, int* __restrict__ toff)
{
  if (threadIdx.x == 0 && blockIdx.x == 0) {
    int s = 0, t = 0;
#pragma unroll
    for (int e = 0; e < NE; ++e) {
      expoff[e] = s;
      toff[e] = t;
      s += cnt[e];
      t += (cnt[e] + 255) >> 8;
    }
    toff[NE] = t;
  }
}

// ---------------- inverse map: pair -> slot ---------------------------------
__global__ __launch_bounds__(256) void fillslot_kernel(
    const int* __restrict__ cnt, const int* __restrict__ expoff,
    const int* __restrict__ bucket, int* __restrict__ pairslot)
{
  const int e = blockIdx.x;
  const int n = cnt[e], off = expoff[e];
  for (int p = threadIdx.x; p < n; p += 256)
    pairslot[bucket[e * CAP + p]] = off + p;
}

// ---------------- pack weights: fp32 [R=K][C=N] -> 8KB linear B tiles -------
// Tile (nt = n>>7, kt = k>>5): byte = r*64 + ((ch ^ f(r))<<4) + (k&7)*2,
// r = n&127, ch = (k>>3)&3, f(r) = (r>>1)&3 -- exactly the LDS image the
// GEMM reads, so B staging is a pure linear 8 KB stream per K-tile.
__global__ __launch_bounds__(256) void pack_kernel(
    const float* __restrict__ src, unsigned short* __restrict__ dst, int R, int C)
{
  __shared__ float tileT[64][68];
  const int ez = blockIdx.z;
  src += (size_t)ez * R * C;
  char* dbytes = (char*)dst + (size_t)ez * R * C * 2;
  const int c0 = blockIdx.x * 64, r0 = blockIdx.y * 64;
  const int tid = threadIdx.x;
  const int cx = tid & 15;
  const int ry = tid >> 4;
#pragma unroll
  for (int i = 0; i < 4; ++i) {
    const int row = ry + i * 16;
    const float4 v = *(const float4*)(src + (size_t)(r0 + row) * C + c0 + cx * 4);
    tileT[cx * 4 + 0][row] = v.x;
    tileT[cx * 4 + 1][row] = v.y;
    tileT[cx * 4 + 2][row] = v.z;
    tileT[cx * 4 + 3][row] = v.w;
  }
  __syncthreads();
#pragma unroll
  for (int i = 0; i < 4; ++i) {
    const int cc = ry + i * 16;
    const int n = c0 + cc;                 // N dim (tile row)
    const int k = r0 + cx * 4;             // K dim
    const float4 v = *(const float4*)(&tileT[cc][cx * 4]);
    short4v o;
    o.x = f2bf(v.x); o.y = f2bf(v.y); o.z = f2bf(v.z); o.w = f2bf(v.w);
    const int nt = n >> 7, r = n & 127;
    const int kt = k >> 5, ch = (k >> 3) & 3;
    const size_t byte = ((size_t)nt * (R >> 5) + kt) * 8192 +
                        r * 64 + ((ch ^ ((r >> 1) & 3)) << 4) + (k & 7) * 2;
    *(short4v*)(dbytes + byte) = o;
  }
}

// ---------------- grouped expert GEMM: 256x128xBK32, dbuf, 3 blocks/CU ------
// 4 waves (2M x 2N), wave = 128x64, acc[8][4]. LDS 48 KB dbuf + rowpair ->
// 3 resident blocks (>=2 staging groups => ~6.1 TB/s per-CU VMEM rate, the
// R1/R7/R9-measured ceiling). Staged volume 1.6-1.7 GB/layer (vs R7 2.2).
// R7 schedule: stage(kt+1) -> compute(kt) -> __syncthreads() (one barrier,
// drain lands ~compute-time after issue; cross-block overlap fills VMEM).
// LAYER 1: hmid[slot] = gelu(Xb[tok] @ W1p + b1)   (K=1024, A gathered)
// LAYER 2: ybuf[slot] = hmid[slot] @ W2p + b2      (K=4096, A contiguous)
template<int LAYER>
__global__ __launch_bounds__(256) void moe_gemm(
    const unsigned short* __restrict__ Abase,
    const unsigned short* __restrict__ Bpack,
    const float* __restrict__ bias,
    const int* __restrict__ cnt,
    const int* __restrict__ expoff,
    const int* __restrict__ toff,
    const int* __restrict__ bucket,
    unsigned short* __restrict__ Obuf)      // hmid (L1) or ybuf (L2)
{
  constexpr int BM = 256, BN = 128, BK = 32;
  constexpr int KDIM = (LAYER == 1) ? D_DIM : F_DIM;
  constexpr int NDIM = (LAYER == 1) ? F_DIM : D_DIM;
  constexpr int KT = KDIM / BK;            // 32 or 128

  // XCD chunk decode, mt fastest (B-panel L2 reuse within a chunk)
  const int q = gridDim.x >> 3;
  const int g = (blockIdx.x & 7) * q + (blockIdx.x >> 3);
  const int ntile = g / MAXT;
  const int mt = g % MAXT;
  if (mt >= toff[NE]) return;
  int e = 0;
  while (mt >= toff[e + 1]) ++e;
  const int mtile = mt - toff[e];
  const int cnt_e = cnt[e];
  const int eoff = expoff[e];

  __shared__ __align__(16) char Alds[2][16384];   // 32 KiB (256 x 64 B)
  __shared__ __align__(16) char Blds[2][8192];    // 16 KiB (128 x 64 B)
  __shared__ int rowpair[BM];

  const int tid = threadIdx.x;
  const int lane = tid & 63;
  const int l15 = lane & 15, lhi = lane >> 4;
  const int wid = tid >> 6;
  const int uw = __builtin_amdgcn_readfirstlane(wid);
  const int wm = wid >> 1, wn = wid & 1;          // 2M x 2N waves

  if (LAYER == 1) {
    if (tid < BM) {
      int pos = mtile * BM + tid;
      rowpair[tid] = (pos < cnt_e) ? bucket[e * CAP + pos] : -1;
    }
    __syncthreads();
  }

  // A: chunk ci = i*256+tid (i=0..3); r = ci>>2, ch = ci&3; source K-chunk
  // pre-swizzled sc = ch ^ f(r) so linear DMA dest == swizzled read image.
  const unsigned short* a_src[4];
#pragma unroll
  for (int i = 0; i < 4; ++i) {
    int ci = i * 256 + tid;
    int r = ci >> 2, ch = ci & 3;
    int sc = ch ^ ((r >> 1) & 3);
    size_t arow;
    if (LAYER == 1) {
      int pair = rowpair[r];
      arow = (pair < 0) ? 0 : (size_t)(pair >> 1);
    } else {
      arow = (size_t)(eoff + mtile * BM + r);      // contiguous slot rows
    }
    a_src[i] = Abase + arow * KDIM + sc * 8;
  }
  // B: packed linear 8 KB tiles (swizzle baked in by pack_kernel)
  const unsigned short* bP = Bpack + (size_t)e * NDIM * KDIM +
      (size_t)ntile * KT * 4096;

  auto stage = [&](int buf, int kt) {
#pragma unroll
    for (int i = 0; i < 4; ++i)
      gload(a_src[i] + kt * BK, &Alds[buf][0] + i * 4096 + uw * 1024);
    const unsigned short* bp = bP + (size_t)kt * 4096;
#pragma unroll
    for (int i = 0; i < 2; ++i)
      gload(bp + (i * 256 + tid) * 8, &Blds[buf][0] + i * 4096 + uw * 1024);
  };

  f32x4 acc[8][4];
#pragma unroll
  for (int m = 0; m < 8; ++m)
#pragma unroll
    for (int n = 0; n < 4; ++n) acc[m][n] = (f32x4){0.f, 0.f, 0.f, 0.f};

  stage(0, 0);
  __syncthreads();

  for (int kt = 0; kt < KT; ++kt) {
    const int b = kt & 1;
    if (kt + 1 < KT) stage(b ^ 1, kt + 1);       // in flight through compute
    short8 bfr[4];
#pragma unroll
    for (int n = 0; n < 4; ++n) {
      const int row = wn * 64 + n * 16 + l15;
      bfr[n] = *(const short8*)(&Blds[b][0] + row * 64 +
                                ((lhi ^ ((row >> 1) & 3)) << 4));
    }
#pragma unroll
    for (int m = 0; m < 8; ++m) {
      const int row = wm * 128 + m * 16 + l15;
      const short8 af = *(const short8*)(&Alds[b][0] + row * 64 +
                                         ((lhi ^ ((row >> 1) & 3)) << 4));
#pragma unroll
      for (int n = 0; n < 4; ++n)
        acc[m][n] = __builtin_amdgcn_mfma_f32_16x16x32_bf16(af, bfr[n], acc[m][n], 0, 0, 0);
    }
    __syncthreads();   // drains this iteration's prefetch + orders buffer reuse
  }

  // epilogue: C/D layout col = lane&15, row = (lane>>4)*4 + j
#pragma unroll
  for (int m = 0; m < 8; ++m) {
#pragma unroll
    for (int j = 0; j < 4; ++j) {
      const int row = wm * 128 + m * 16 + lhi * 4 + j;
      if (mtile * BM + row >= cnt_e) continue;
      const size_t slot = (size_t)(eoff + mtile * BM + row);
#pragma unroll
      for (int n = 0; n < 4; ++n) {
        const int col = ntile * BN + wn * 64 + n * 16 + l15;
        float val = acc[m][n][j] + bias[e * NDIM + col];
        if (LAYER == 1) {
          float gl = 0.5f * val * (1.f + erff(val * 0.70710678118654752f));
          Obuf[slot * F_DIM + col] = (unsigned short)f2bf(gl);
        } else {
          Obuf[slot * D_DIM + col] = (unsigned short)f2bf(val);
        }
      }
    }
  }
}

// ---------------- combine: out[t] = w0*y[slot0] + w1*y[slot1] ---------------
__global__ __launch_bounds__(256) void combine_kernel(
    const unsigned short* __restrict__ ybuf, const float* __restrict__ pairw,
    const int* __restrict__ pairslot, float* __restrict__ out)
{
  const int t = blockIdx.x;
  const int tid = threadIdx.x;
  const float w0 = pairw[t * 2], w1 = pairw[t * 2 + 1];
  const int s0 = pairslot[t * 2], s1 = pairslot[t * 2 + 1];
  const short4v a = ((const short4v*)(ybuf + (size_t)s0 * D_DIM))[tid];
  const short4v b = ((const short4v*)(ybuf + (size_t)s1 * D_DIM))[tid];
  float4 o;
  o.x = w0 * bf2f(a.x) + w1 * bf2f(b.x);
  o.y = w0 * bf2f(a.y) + w1 * bf2f(b.y);
  o.z = w0 * bf2f(a.z) + w1 * bf2f(b.z);
  o.w = w0 * bf2f(a.w) + w1 * bf2f(b.w);
  ((float4*)(out + (size_t)t * D_DIM))[tid] = o;
}

// ---------------- launch ----------------------------------------------------
extern "C" void kernel_launch(void* const* d_in, const int* in_sizes, int n_in,
                              void* d_out, int out_size, void* d_ws, size_t ws_size,
                              hipStream_t stream)
{
  const float* X  = (const float*)d_in[0];
  const float* Wg = (const float*)d_in[1];
  const float* bg = (const float*)d_in[2];
  const float* W1 = (const float*)d_in[3];
  const float* b1 = (const float*)d_in[4];
  const float* W2 = (const float*)d_in[5];
  const float* b2 = (const float*)d_in[6];
  float* out = (float*)d_out;

  char* ws = (char*)d_ws;
  size_t off = 0;
  auto alloc = [&](size_t sz) {
    size_t o = off;
    off = (off + sz + 255) & ~(size_t)255;
    return o;
  };
  int*            cnt      = (int*)(ws + alloc(NE * sizeof(int)));
  int*            expoff   = (int*)(ws + alloc(NE * sizeof(int)));
  int*            toff     = (int*)(ws + alloc((NE + 1) * sizeof(int)));
  int*            bucket   = (int*)(ws + alloc((size_t)NE * CAP * sizeof(int)));
  float*          pairw    = (float*)(ws + alloc((size_t)N_TOK * 2 * sizeof(float)));
  int*            pairslot = (int*)(ws + alloc((size_t)N_TOK * 2 * sizeof(int)));
  unsigned short* Xb       = (unsigned short*)(ws + alloc((size_t)N_TOK * D_DIM * 2));
  unsigned short* W1p      = (unsigned short*)(ws + alloc((size_t)NE * D_DIM * F_DIM * 2));
  unsigned short* W2p      = (unsigned short*)(ws + alloc((size_t)NE * D_DIM * F_DIM * 2));
  unsigned short* hmid     = (unsigned short*)(ws + alloc((size_t)(N_TOK * 2 + 256) * F_DIM * 2));
  unsigned short* ybuf     = W1p;   // W1p dead after GEMM1

  hipMemsetAsync(cnt, 0, NE * sizeof(int), stream);

  pack_kernel<<<dim3(F_DIM / 64, D_DIM / 64, NE), 256, 0, stream>>>(
      W1, W1p, D_DIM, F_DIM);
  pack_kernel<<<dim3(D_DIM / 64, F_DIM / 64, NE), 256, 0, stream>>>(
      W2, W2p, F_DIM, D_DIM);
  gate_kernel<<<N_TOK, 256, 0, stream>>>(X, Wg, bg, cnt, bucket, pairw, Xb);
  prefix_kernel<<<1, 64, 0, stream>>>(cnt, expoff, toff);
  fillslot_kernel<<<NE, 256, 0, stream>>>(cnt, expoff, bucket, pairslot);

  moe_gemm<1><<<MAXT * (F_DIM / 128), 256, 0, stream>>>(   // 2304 blocks (%8==0)
      Xb, W1p, b1, cnt, expoff, toff, bucket, hmid);
  moe_gemm<2><<<MAXT * (D_DIM / 128), 256, 0, stream>>>(   // 576 blocks (%8==0)
      hmid, W2p, b2, cnt, expoff, toff, bucket, ybuf);
  combine_kernel<<<N_TOK, 256, 0, stream>>>(ybuf, pairw, pairslot, out);
}

// Round 13
// 907.203 us; speedup vs baseline: 1.5338x; 1.5338x over previous
//
#include <hip/hip_runtime.h>
#include <hip/hip_bf16.h>
#include <cstdint>
#include <math.h>

#define N_TOK 8192
#define D_DIM 1024
#define F_DIM 4096
#define NE 8
#define CAP 8192
#define MAXT 136   // max sum_e ceil(cnt_e/128)

typedef __attribute__((ext_vector_type(8))) short short8;
typedef __attribute__((ext_vector_type(4))) short short4v;
typedef __attribute__((ext_vector_type(4))) float f32x4;

__device__ __forceinline__ short f2bf(float f) {
  __bf16 b = (__bf16)f;
  return *(short*)&b;
}
__device__ __forceinline__ float bf2f(short u) {
  union { unsigned int i; float f; } c;
  c.i = ((unsigned int)(unsigned short)u) << 16;
  return c.f;
}

// ---------------- gating + fused X->bf16 ------------------------------------
__global__ __launch_bounds__(256) void gate_kernel(
    const float* __restrict__ X, const float* __restrict__ Wg,
    const float* __restrict__ bg, int* __restrict__ cnt,
    int* __restrict__ bucket, float* __restrict__ pairw,
    unsigned short* __restrict__ Xb)
{
  const int token = blockIdx.x;
  const int tid = threadIdx.x;
  const float4* x4 = (const float4*)(X + (size_t)token * D_DIM);
  const float4* wg4 = (const float4*)Wg;
  float part[NE];
#pragma unroll
  for (int e = 0; e < NE; ++e) part[e] = 0.f;
  const float4 xv = x4[tid];
#pragma unroll
  for (int e = 0; e < NE; ++e) {
    const float4 wv = wg4[e * (D_DIM / 4) + tid];
    part[e] = fmaf(xv.x, wv.x, fmaf(xv.y, wv.y, fmaf(xv.z, wv.z, fmaf(xv.w, wv.w, part[e]))));
  }
  short4v o;
  o.x = f2bf(xv.x); o.y = f2bf(xv.y); o.z = f2bf(xv.z); o.w = f2bf(xv.w);
  ((short4v*)(Xb + (size_t)token * D_DIM))[tid] = o;

#pragma unroll
  for (int e = 0; e < NE; ++e) {
#pragma unroll
    for (int off = 32; off > 0; off >>= 1) part[e] += __shfl_down(part[e], off);
  }
  __shared__ float wsum[4][NE];
  const int wave = tid >> 6;
  if ((tid & 63) == 0) {
#pragma unroll
    for (int e = 0; e < NE; ++e) wsum[wave][e] = part[e];
  }
  __syncthreads();
  if (tid == 0) {
    float lg[NE];
#pragma unroll
    for (int e = 0; e < NE; ++e)
      lg[e] = wsum[0][e] + wsum[1][e] + wsum[2][e] + wsum[3][e] + bg[e];
    int e0 = 0;
#pragma unroll
    for (int e = 1; e < NE; ++e) if (lg[e] > lg[e0]) e0 = e;     // jax tie-break: lower idx
    int e1 = (e0 == 0) ? 1 : 0;
#pragma unroll
    for (int e = 0; e < NE; ++e) if (e != e0 && lg[e] > lg[e1]) e1 = e;
    float p1 = expf(lg[e1] - lg[e0]);            // p0 = 1; softmax denom cancels
    float inv = 1.f / (1.f + p1);
    pairw[token * 2]     = inv;
    pairw[token * 2 + 1] = p1 * inv;
    int pos0 = atomicAdd(&cnt[e0], 1);
    bucket[e0 * CAP + pos0] = token * 2;
    int pos1 = atomicAdd(&cnt[e1], 1);
    bucket[e1 * CAP + pos1] = token * 2 + 1;
  }
}

// ---------------- prefix sums (row offsets + 128-row tile offsets) ----------
__global__ void prefix_kernel(const int* __restrict__ cnt,
                              int* __restrict__ expoff, int* __restrict__ toff)
{
  if (threadIdx.x == 0 && blockIdx.x == 0) {
    int s = 0, t = 0;
#pragma unroll
    for (int e = 0; e < NE; ++e) {
      expoff[e] = s;
      toff[e] = t;
      s += cnt[e];
      t += (cnt[e] + 127) >> 7;
    }
    toff[NE] = t;
  }
}

// ---------------- inverse map: pair -> slot ---------------------------------
__global__ __launch_bounds__(256) void fillslot_kernel(
    const int* __restrict__ cnt, const int* __restrict__ expoff,
    const int* __restrict__ bucket, int* __restrict__ pairslot)
{
  const int e = blockIdx.x;
  const int n = cnt[e], off = expoff[e];
  for (int p = threadIdx.x; p < n; p += 256)
    pairslot[bucket[e * CAP + p]] = off + p;
}

// ---------------- both weight transposes in ONE launch ----------------------
// z < NE: W1 (R=D,C=F) -> W1t[C][R];  z >= NE: W2 (R=F,C=D) -> W2t[C][R].
// Grid (64,16,2*NE); for W2 the (x,y) roles swap so both shapes are covered.
__global__ __launch_bounds__(256) void transpose_both_kernel(
    const float* __restrict__ W1, const float* __restrict__ W2,
    unsigned short* __restrict__ W1t, unsigned short* __restrict__ W2t)
{
  __shared__ float tileT[64][68];
  const int z = blockIdx.z;
  const bool is1 = (z < NE);
  const int ez = is1 ? z : z - NE;
  const int R = is1 ? D_DIM : F_DIM;
  const int C = is1 ? F_DIM : D_DIM;
  const float* src = (is1 ? W1 : W2) + (size_t)ez * D_DIM * F_DIM;
  unsigned short* dst = (is1 ? W1t : W2t) + (size_t)ez * D_DIM * F_DIM;
  const int c0 = (is1 ? blockIdx.x : blockIdx.y) * 64;
  const int r0 = (is1 ? blockIdx.y : blockIdx.x) * 64;
  const int tid = threadIdx.x;
  const int cx = tid & 15;
  const int ry = tid >> 4;
#pragma unroll
  for (int i = 0; i < 4; ++i) {
    const int row = ry + i * 16;
    const float4 v = *(const float4*)(src + (size_t)(r0 + row) * C + c0 + cx * 4);
    tileT[cx * 4 + 0][row] = v.x;
    tileT[cx * 4 + 1][row] = v.y;
    tileT[cx * 4 + 2][row] = v.z;
    tileT[cx * 4 + 3][row] = v.w;
  }
  __syncthreads();
#pragma unroll
  for (int i = 0; i < 4; ++i) {
    const int cc = ry + i * 16;
    const float4 v = *(const float4*)(&tileT[cc][cx * 4]);
    short4v o;
    o.x = f2bf(v.x); o.y = f2bf(v.y); o.z = f2bf(v.z); o.w = f2bf(v.w);
    *(short4v*)(dst + (size_t)(c0 + cc) * R + r0 + cx * 4) = o;
  }
}

// ---------------- grouped expert GEMM, 128x128, 2 blocks/CU (R7) ------------
// LAYER 1: hmid[slot] = gelu(Xb[tok] @ W1t + b1)   (K=1024, N=4096, A gathered)
// LAYER 2: ybuf[slot] = hmid[slot] @ W2t + b2      (K=4096, N=1024, A dense)
// 4 waves (2M x 2N), per-wave 64x64, acc[4][4] (88 VGPR, no spills).
// LDS 64.5 KB -> 2 blocks/CU. Staging: global_load_lds w16, uniform LDS dest,
// source column XOR-preswizzled -> conflict-free swizzled ds_read_b128.
// This config sits at the measured memory-path roofline (~6.2 TB/s of
// staged+written traffic) -- six alternative schedules/tilings (R2-R12) all
// tied or regressed; volume/rate trade 1:1 at this working-set locality.
template<int LAYER>
__global__ __launch_bounds__(256) void moe_gemm(
    const unsigned short* __restrict__ Abase,
    const unsigned short* __restrict__ Bt,
    const float* __restrict__ bias,
    const int* __restrict__ cnt,
    const int* __restrict__ expoff,
    const int* __restrict__ toff,
    const int* __restrict__ bucket,
    unsigned short* __restrict__ Obuf)      // hmid (L1) or ybuf (L2)
{
  constexpr int BM = 128, BN = 128, BK = 64;
  constexpr int KDIM = (LAYER == 1) ? D_DIM : F_DIM;
  constexpr int NDIM = (LAYER == 1) ? F_DIM : D_DIM;
  constexpr int KT = KDIM / BK;
  constexpr int SLOT = BM * BK * 2;          // 16 KiB

  const int q = gridDim.x >> 3;
  const int g = (blockIdx.x & 7) * q + (blockIdx.x >> 3);
  const int ntile = g / MAXT;
  const int mt_glob = g % MAXT;
  if (mt_glob >= toff[NE]) return;
  int e = 0;
  while (mt_glob >= toff[e + 1]) ++e;
  const int mtile = mt_glob - toff[e];
  const int cnt_e = cnt[e];
  const int eoff = expoff[e];

  __shared__ __align__(16) char Alds[2][SLOT];   // 32 KiB
  __shared__ __align__(16) char Blds[2][SLOT];   // 32 KiB
  __shared__ int rowpair[BM];

  const int tid = threadIdx.x;
  const int lane = tid & 63;
  const int l15 = lane & 15, lhi = lane >> 4;
  const int wid = tid >> 6;
  const int uw = __builtin_amdgcn_readfirstlane(wid);
  const int wm = wid >> 1, wn = wid & 1;

  if (LAYER == 1) {
    if (tid < BM) {
      int pos = mtile * BM + tid;
      rowpair[tid] = (pos < cnt_e) ? bucket[e * CAP + pos] : -1;
    }
    __syncthreads();
  }

  const unsigned short* a_src[4];
  const unsigned short* b_src[4];
#pragma unroll
  for (int i = 0; i < 4; ++i) {
    int ci = i * 256 + tid;
    int r = ci >> 3, c = ci & 7;
    int sc = c ^ (r & 7);
    size_t arow;
    if (LAYER == 1) {
      int pair = rowpair[r];
      arow = (pair < 0) ? 0 : (size_t)(pair >> 1);
    } else {
      arow = (size_t)(eoff + mtile * BM + r);        // contiguous slot rows
    }
    a_src[i] = Abase + arow * KDIM + sc * 8;
    int ng = ntile * BN + r;
    b_src[i] = Bt + (size_t)e * NDIM * KDIM + (size_t)ng * KDIM + sc * 8;
  }

  auto stage = [&](int buf, int kt) {
#pragma unroll
    for (int i = 0; i < 4; ++i)
      __builtin_amdgcn_global_load_lds(
          (const __attribute__((address_space(1))) uint32_t*)(a_src[i] + kt * BK),
          (__attribute__((address_space(3))) uint32_t*)(&Alds[buf][0] + i * 4096 + uw * 1024),
          16, 0, 0);
#pragma unroll
    for (int i = 0; i < 4; ++i)
      __builtin_amdgcn_global_load_lds(
          (const __attribute__((address_space(1))) uint32_t*)(b_src[i] + kt * BK),
          (__attribute__((address_space(3))) uint32_t*)(&Blds[buf][0] + i * 4096 + uw * 1024),
          16, 0, 0);
  };

  f32x4 acc[4][4];
#pragma unroll
  for (int m = 0; m < 4; ++m)
#pragma unroll
    for (int n = 0; n < 4; ++n) acc[m][n] = (f32x4){0.f, 0.f, 0.f, 0.f};

  stage(0, 0);
  __syncthreads();

  for (int kt = 0; kt < KT; ++kt) {
    const int b = kt & 1;
    if (kt + 1 < KT) stage(b ^ 1, kt + 1);
#pragma unroll
    for (int kk = 0; kk < 2; ++kk) {
      const int c16 = kk * 4 + lhi;
      short8 bfr[4];
#pragma unroll
      for (int n = 0; n < 4; ++n) {
        int row = wn * 64 + n * 16 + l15;
        bfr[n] = *(const short8*)(&Blds[b][0] + row * 128 + ((c16 ^ (row & 7)) * 16));
      }
#pragma unroll
      for (int m = 0; m < 4; ++m) {
        int row = wm * 64 + m * 16 + l15;
        short8 af = *(const short8*)(&Alds[b][0] + row * 128 + ((c16 ^ (row & 7)) * 16));
#pragma unroll
        for (int n = 0; n < 4; ++n)
          acc[m][n] = __builtin_amdgcn_mfma_f32_16x16x32_bf16(af, bfr[n], acc[m][n], 0, 0, 0);
      }
    }
    __syncthreads();
  }

  // epilogue: C/D layout col = lane&15, row = (lane>>4)*4 + j; plain stores.
#pragma unroll
  for (int m = 0; m < 4; ++m) {
#pragma unroll
    for (int j = 0; j < 4; ++j) {
      const int row = wm * 64 + m * 16 + lhi * 4 + j;
      if (mtile * BM + row >= cnt_e) continue;
      const size_t slot = (size_t)(eoff + mtile * BM + row);
#pragma unroll
      for (int n = 0; n < 4; ++n) {
        const int col = ntile * BN + wn * 64 + n * 16 + l15;
        float val = acc[m][n][j] + bias[e * NDIM + col];
        if (LAYER == 1) {
          float gl = 0.5f * val * (1.f + erff(val * 0.70710678118654752f));
          Obuf[slot * F_DIM + col] = (unsigned short)f2bf(gl);
        } else {
          Obuf[slot * D_DIM + col] = (unsigned short)f2bf(val);
        }
      }
    }
  }
}

// ---------------- combine: out[t] = w0*y[slot0] + w1*y[slot1] ---------------
__global__ __launch_bounds__(256) void combine_kernel(
    const unsigned short* __restrict__ ybuf, const float* __restrict__ pairw,
    const int* __restrict__ pairslot, float* __restrict__ out)
{
  const int t = blockIdx.x;
  const int tid = threadIdx.x;
  const float w0 = pairw[t * 2], w1 = pairw[t * 2 + 1];
  const int s0 = pairslot[t * 2], s1 = pairslot[t * 2 + 1];
  const short4v a = ((const short4v*)(ybuf + (size_t)s0 * D_DIM))[tid];
  const short4v b = ((const short4v*)(ybuf + (size_t)s1 * D_DIM))[tid];
  float4 o;
  o.x = w0 * bf2f(a.x) + w1 * bf2f(b.x);
  o.y = w0 * bf2f(a.y) + w1 * bf2f(b.y);
  o.z = w0 * bf2f(a.z) + w1 * bf2f(b.z);
  o.w = w0 * bf2f(a.w) + w1 * bf2f(b.w);
  ((float4*)(out + (size_t)t * D_DIM))[tid] = o;
}

// ---------------- launch ----------------------------------------------------
extern "C" void kernel_launch(void* const* d_in, const int* in_sizes, int n_in,
                              void* d_out, int out_size, void* d_ws, size_t ws_size,
                              hipStream_t stream)
{
  const float* X  = (const float*)d_in[0];
  const float* Wg = (const float*)d_in[1];
  const float* bg = (const float*)d_in[2];
  const float* W1 = (const float*)d_in[3];
  const float* b1 = (const float*)d_in[4];
  const float* W2 = (const float*)d_in[5];
  const float* b2 = (const float*)d_in[6];
  float* out = (float*)d_out;

  char* ws = (char*)d_ws;
  size_t off = 0;
  auto alloc = [&](size_t sz) {
    size_t o = off;
    off = (off + sz + 255) & ~(size_t)255;
    return o;
  };
  int*            cnt      = (int*)(ws + alloc(NE * sizeof(int)));
  int*            expoff   = (int*)(ws + alloc(NE * sizeof(int)));
  int*            toff     = (int*)(ws + alloc((NE + 1) * sizeof(int)));
  int*            bucket   = (int*)(ws + alloc((size_t)NE * CAP * sizeof(int)));
  float*          pairw    = (float*)(ws + alloc((size_t)N_TOK * 2 * sizeof(float)));
  int*            pairslot = (int*)(ws + alloc((size_t)N_TOK * 2 * sizeof(int)));
  unsigned short* Xb       = (unsigned short*)(ws + alloc((size_t)N_TOK * D_DIM * 2));
  unsigned short* W1t      = (unsigned short*)(ws + alloc((size_t)NE * D_DIM * F_DIM * 2));
  unsigned short* W2t      = (unsigned short*)(ws + alloc((size_t)NE * D_DIM * F_DIM * 2));
  unsigned short* hmid     = (unsigned short*)(ws + alloc((size_t)(N_TOK * 2 + 256) * F_DIM * 2));
  unsigned short* ybuf     = W1t;   // W1t dead after GEMM1; ybuf written in GEMM2

  hipMemsetAsync(cnt, 0, NE * sizeof(int), stream);

  gate_kernel<<<N_TOK, 256, 0, stream>>>(X, Wg, bg, cnt, bucket, pairw, Xb);
  transpose_both_kernel<<<dim3(64, 16, 2 * NE), 256, 0, stream>>>(W1, W2, W1t, W2t);
  prefix_kernel<<<1, 64, 0, stream>>>(cnt, expoff, toff);
  fillslot_kernel<<<NE, 256, 0, stream>>>(cnt, expoff, bucket, pairslot);

  moe_gemm<1><<<MAXT * (F_DIM / 128), 256, 0, stream>>>(   // 4352 blocks (%8==0)
      Xb, W1t, b1, cnt, expoff, toff, bucket, hmid);
  moe_gemm<2><<<MAXT * (D_DIM / 128), 256, 0, stream>>>(   // 1088 blocks (%8==0)
      hmid, W2t, b2, cnt, expoff, toff, bucket, ybuf);
  combine_kernel<<<N_TOK, 256, 0, stream>>>(ybuf, pairw, pairslot, out);
}

// Round 14
// 826.550 us; speedup vs baseline: 1.6834x; 1.0976x over previous
//
#include <hip/hip_runtime.h>
#include <hip/hip_bf16.h>
#include <cstdint>
#include <math.h>

#define N_TOK 8192
#define D_DIM 1024
#define F_DIM 4096
#define NE 8
#define CAP 8192
#define MAXT 72    // max sum_e ceil(cnt_e/256) = 71, padded

typedef __attribute__((ext_vector_type(8))) short short8;
typedef __attribute__((ext_vector_type(4))) short short4v;
typedef __attribute__((ext_vector_type(4))) float f32x4;

__device__ __forceinline__ short f2bf(float f) {
  __bf16 b = (__bf16)f;
  return *(short*)&b;
}
__device__ __forceinline__ float bf2f(short u) {
  union { unsigned int i; float f; } c;
  c.i = ((unsigned int)(unsigned short)u) << 16;
  return c.f;
}
__device__ __forceinline__ void gload(const void* g, void* l) {
  __builtin_amdgcn_global_load_lds(
      (const __attribute__((address_space(1))) uint32_t*)g,
      (__attribute__((address_space(3))) uint32_t*)l, 16, 0, 0);
}

// ---------------- gating + fused X->bf16 ------------------------------------
__global__ __launch_bounds__(256) void gate_kernel(
    const float* __restrict__ X, const float* __restrict__ Wg,
    const float* __restrict__ bg, int* __restrict__ cnt,
    int* __restrict__ bucket, float* __restrict__ pairw,
    unsigned short* __restrict__ Xb)
{
  const int token = blockIdx.x;
  const int tid = threadIdx.x;
  const float4* x4 = (const float4*)(X + (size_t)token * D_DIM);
  const float4* wg4 = (const float4*)Wg;
  float part[NE];
#pragma unroll
  for (int e = 0; e < NE; ++e) part[e] = 0.f;
  const float4 xv = x4[tid];
#pragma unroll
  for (int e = 0; e < NE; ++e) {
    const float4 wv = wg4[e * (D_DIM / 4) + tid];
    part[e] = fmaf(xv.x, wv.x, fmaf(xv.y, wv.y, fmaf(xv.z, wv.z, fmaf(xv.w, wv.w, part[e]))));
  }
  short4v o;
  o.x = f2bf(xv.x); o.y = f2bf(xv.y); o.z = f2bf(xv.z); o.w = f2bf(xv.w);
  ((short4v*)(Xb + (size_t)token * D_DIM))[tid] = o;

#pragma unroll
  for (int e = 0; e < NE; ++e) {
#pragma unroll
    for (int off = 32; off > 0; off >>= 1) part[e] += __shfl_down(part[e], off);
  }
  __shared__ float wsum[4][NE];
  const int wave = tid >> 6;
  if ((tid & 63) == 0) {
#pragma unroll
    for (int e = 0; e < NE; ++e) wsum[wave][e] = part[e];
  }
  __syncthreads();
  if (tid == 0) {
    float lg[NE];
#pragma unroll
    for (int e = 0; e < NE; ++e)
      lg[e] = wsum[0][e] + wsum[1][e] + wsum[2][e] + wsum[3][e] + bg[e];
    int e0 = 0;
#pragma unroll
    for (int e = 1; e < NE; ++e) if (lg[e] > lg[e0]) e0 = e;     // jax tie-break: lower idx
    int e1 = (e0 == 0) ? 1 : 0;
#pragma unroll
    for (int e = 0; e < NE; ++e) if (e != e0 && lg[e] > lg[e1]) e1 = e;
    float p1 = expf(lg[e1] - lg[e0]);            // p0 = 1; softmax denom cancels
    float inv = 1.f / (1.f + p1);
    pairw[token * 2]     = inv;
    pairw[token * 2 + 1] = p1 * inv;
    int pos0 = atomicAdd(&cnt[e0], 1);
    bucket[e0 * CAP + pos0] = token * 2;
    int pos1 = atomicAdd(&cnt[e1], 1);
    bucket[e1 * CAP + pos1] = token * 2 + 1;
  }
}

// ---------------- prefix sums (row offsets + 256-row tile offsets) ----------
__global__ void prefix_kernel(const int* __restrict__ cnt,
                              int* __restrict__ expoff, int* __restrict__ toff)
{
  if (threadIdx.x == 0 && blockIdx.x == 0) {
    int s = 0, t = 0;
#pragma unroll
    for (int e = 0; e < NE; ++e) {
      expoff[e] = s;
      toff[e] = t;
      s += cnt[e];
      t += (cnt[e] + 255) >> 8;
    }
    toff[NE] = t;
  }
}

// ---------------- inverse map: pair -> slot ---------------------------------
__global__ __launch_bounds__(256) void fillslot_kernel(
    const int* __restrict__ cnt, const int* __restrict__ expoff,
    const int* __restrict__ bucket, int* __restrict__ pairslot)
{
  const int e = blockIdx.x;
  const int n = cnt[e], off = expoff[e];
  for (int p = threadIdx.x; p < n; p += 256)
    pairslot[bucket[e * CAP + p]] = off + p;
}

// ---------------- both weight transposes in ONE launch ----------------------
__global__ __launch_bounds__(256) void transpose_both_kernel(
    const float* __restrict__ W1, const float* __restrict__ W2,
    unsigned short* __restrict__ W1t, unsigned short* __restrict__ W2t)
{
  __shared__ float tileT[64][68];
  const int z = blockIdx.z;
  const bool is1 = (z < NE);
  const int ez = is1 ? z : z - NE;
  const int R = is1 ? D_DIM : F_DIM;
  const int C = is1 ? F_DIM : D_DIM;
  const float* src = (is1 ? W1 : W2) + (size_t)ez * D_DIM * F_DIM;
  unsigned short* dst = (is1 ? W1t : W2t) + (size_t)ez * D_DIM * F_DIM;
  const int c0 = (is1 ? blockIdx.x : blockIdx.y) * 64;
  const int r0 = (is1 ? blockIdx.y : blockIdx.x) * 64;
  const int tid = threadIdx.x;
  const int cx = tid & 15;
  const int ry = tid >> 4;
#pragma unroll
  for (int i = 0; i < 4; ++i) {
    const int row = ry + i * 16;
    const float4 v = *(const float4*)(src + (size_t)(r0 + row) * C + c0 + cx * 4);
    tileT[cx * 4 + 0][row] = v.x;
    tileT[cx * 4 + 1][row] = v.y;
    tileT[cx * 4 + 2][row] = v.z;
    tileT[cx * 4 + 3][row] = v.w;
  }
  __syncthreads();
#pragma unroll
  for (int i = 0; i < 4; ++i) {
    const int cc = ry + i * 16;
    const float4 v = *(const float4*)(&tileT[cc][cx * 4]);
    short4v o;
    o.x = f2bf(v.x); o.y = f2bf(v.y); o.z = f2bf(v.z); o.w = f2bf(v.w);
    *(short4v*)(dst + (size_t)(c0 + cc) * R + r0 + cx * 4) = o;
  }
}

// ---------------- grouped expert GEMM: 256x128x64, ring-3, vmcnt(6) ---------
// 512 threads, 8 waves (4M x 2N), wave = 64x64, acc[4][4]. All LDS slots are
// 64 rows x 128 B = 8 KB with the proven c^(r&7) swizzle (0 conflicts):
// A = ring3 x 4 quarters (96 KB), B = ring3 x 2 halves (48 KB). Per tile U:
// 2 phases (kk); each phase: ds_read af[4]+bfr[4] -> issue 3 of tile U+2's 6
// gloads -> lgkmcnt(0)+sched_barrier -> setprio+16 MFMA -> barrier. Loop-top:
// vmcnt(6) (tile U landed, U+1's 6 in flight -- never drains mid-loop).
// Ledger: prologue stages tiles 0,1 (12 out). top(U): 12 -> wait 6; during U
// stage U+2 (+6) -> 12. WAR: staging U+2 overwrites U-1's ring slot, last
// read >=1 barrier earlier. Tail: no stage for U+2>=KT; top(KT-1): vmcnt(0).
template<int LAYER>
__global__ __launch_bounds__(512) void moe_gemm(
    const unsigned short* __restrict__ Abase,
    const unsigned short* __restrict__ Bt,
    const float* __restrict__ bias,
    const int* __restrict__ cnt,
    const int* __restrict__ expoff,
    const int* __restrict__ toff,
    const int* __restrict__ bucket,
    unsigned short* __restrict__ Obuf)      // hmid (L1) or ybuf (L2)
{
  constexpr int BM = 256, BN = 128, BK = 64;
  constexpr int KDIM = (LAYER == 1) ? D_DIM : F_DIM;
  constexpr int NDIM = (LAYER == 1) ? F_DIM : D_DIM;
  constexpr int KT = KDIM / BK;            // 16 or 64

  const int q = gridDim.x >> 3;
  const int g = (blockIdx.x & 7) * q + (blockIdx.x >> 3);
  const int ntile = g / MAXT;
  const int mt = g % MAXT;
  if (mt >= toff[NE]) return;
  int e = 0;
  while (mt >= toff[e + 1]) ++e;
  const int mtile = mt - toff[e];
  const int cnt_e = cnt[e];
  const int eoff = expoff[e];

  __shared__ __align__(16) char Alds[12 * 8192];   // 96 KiB: ring3 x 4 quarters
  __shared__ __align__(16) char Blds[6 * 8192];    // 48 KiB: ring3 x 2 halves
  __shared__ int rowpair[BM];

  const int tid = threadIdx.x;
  const int lane = tid & 63;
  const int l15 = lane & 15, lhi = lane >> 4;
  const int wid = tid >> 6;
  const int uw = __builtin_amdgcn_readfirstlane(wid);
  const int wm = wid >> 1, wn = wid & 1;           // 4M x 2N

  if (LAYER == 1) {
    if (tid < BM) {
      int pos = mtile * BM + tid;
      rowpair[tid] = (pos < cnt_e) ? bucket[e * CAP + pos] : -1;
    }
    __syncthreads();
  }

  // staging geometry: thread stages chunk (r = tid>>3, c = tid&7) of each
  // 64x64 slot; source column pre-swizzled sc = c ^ (r&7) so linear DMA dest
  // (slotbase + tid*16) equals the swizzled read image.
  const int sr = tid >> 3, scol = (tid & 7) ^ (sr & 7);
  const unsigned short* a_src[4];
#pragma unroll
  for (int qq = 0; qq < 4; ++qq) {
    size_t arow;
    if (LAYER == 1) {
      int pair = rowpair[qq * 64 + sr];
      arow = (pair < 0) ? 0 : (size_t)(pair >> 1);
    } else {
      arow = (size_t)(eoff + mtile * BM + qq * 64 + sr);
    }
    a_src[qq] = Abase + arow * KDIM + scol * 8;
  }
  const unsigned short* b_src[2];
#pragma unroll
  for (int h = 0; h < 2; ++h)
    b_src[h] = Bt + (size_t)e * NDIM * KDIM +
               (size_t)(ntile * BN + h * 64 + sr) * KDIM + scol * 8;

  auto gA = [&](int ring, int qq, int V) {
    gload(a_src[qq] + V * BK, &Alds[0] + (ring * 4 + qq) * 8192 + uw * 1024);
  };
  auto gB = [&](int ring, int h, int V) {
    gload(b_src[h] + V * BK, &Blds[0] + (ring * 2 + h) * 8192 + uw * 1024);
  };

  f32x4 acc[4][4];
#pragma unroll
  for (int m = 0; m < 4; ++m)
#pragma unroll
    for (int n = 0; n < 4; ++n) acc[m][n] = (f32x4){0.f, 0.f, 0.f, 0.f};

  // prologue: stage tiles 0 (ring 0) and 1 (ring 1): 12 gloads outstanding
  gA(0, 0, 0); gA(0, 1, 0); gA(0, 2, 0); gA(0, 3, 0); gB(0, 0, 0); gB(0, 1, 0);
  gA(1, 0, 1); gA(1, 1, 1); gA(1, 2, 1); gA(1, 3, 1); gB(1, 0, 1); gB(1, 1, 1);

  int rU = 0;
  for (int U = 0; U < KT; ++U) {
    if (U + 1 < KT) asm volatile("s_waitcnt vmcnt(6)" ::: "memory");
    else            asm volatile("s_waitcnt vmcnt(0)" ::: "memory");
    __builtin_amdgcn_sched_barrier(0);
    __builtin_amdgcn_s_barrier();

    int rV = rU + 2; if (rV >= 3) rV -= 3;
    const bool st = (U + 2 < KT);
    const char* aSlot = &Alds[0] + (rU * 4 + wm) * 8192;
    const char* bSlot = &Blds[0] + (rU * 2 + wn) * 8192;

#pragma unroll
    for (int kk = 0; kk < 2; ++kk) {
      const int c16 = kk * 4 + lhi;
      short8 bfr[4], af[4];
#pragma unroll
      for (int n = 0; n < 4; ++n) {
        const int row = n * 16 + l15;
        bfr[n] = *(const short8*)(bSlot + row * 128 + ((c16 ^ (row & 7)) << 4));
      }
#pragma unroll
      for (int m = 0; m < 4; ++m) {
        const int row = m * 16 + l15;
        af[m] = *(const short8*)(aSlot + row * 128 + ((c16 ^ (row & 7)) << 4));
      }
      if (st) {
        if (kk == 0) { gA(rV, 0, U + 2); gA(rV, 1, U + 2); gB(rV, 0, U + 2); }
        else         { gA(rV, 2, U + 2); gA(rV, 3, U + 2); gB(rV, 1, U + 2); }
      }
      asm volatile("s_waitcnt lgkmcnt(0)" ::: "memory");
      __builtin_amdgcn_sched_barrier(0);
      __builtin_amdgcn_s_setprio(1);
#pragma unroll
      for (int m = 0; m < 4; ++m)
#pragma unroll
        for (int n = 0; n < 4; ++n)
          acc[m][n] = __builtin_amdgcn_mfma_f32_16x16x32_bf16(af[m], bfr[n], acc[m][n], 0, 0, 0);
      __builtin_amdgcn_s_setprio(0);
      __builtin_amdgcn_s_barrier();
    }
    rU = (rU + 1 == 3) ? 0 : rU + 1;
  }

  // epilogue: C/D layout col = lane&15, row = (lane>>4)*4 + j
#pragma unroll
  for (int m = 0; m < 4; ++m) {
#pragma unroll
    for (int j = 0; j < 4; ++j) {
      const int row = wm * 64 + m * 16 + lhi * 4 + j;
      if (mtile * BM + row >= cnt_e) continue;
      const size_t slot = (size_t)(eoff + mtile * BM + row);
#pragma unroll
      for (int n = 0; n < 4; ++n) {
        const int col = ntile * BN + wn * 64 + n * 16 + l15;
        float val = acc[m][n][j] + bias[e * NDIM + col];
        if (LAYER == 1) {
          float gl = 0.5f * val * (1.f + erff(val * 0.70710678118654752f));
          Obuf[slot * F_DIM + col] = (unsigned short)f2bf(gl);
        } else {
          Obuf[slot * D_DIM + col] = (unsigned short)f2bf(val);
        }
      }
    }
  }
}

// ---------------- combine: out[t] = w0*y[slot0] + w1*y[slot1] ---------------
__global__ __launch_bounds__(256) void combine_kernel(
    const unsigned short* __restrict__ ybuf, const float* __restrict__ pairw,
    const int* __restrict__ pairslot, float* __restrict__ out)
{
  const int t = blockIdx.x;
  const int tid = threadIdx.x;
  const float w0 = pairw[t * 2], w1 = pairw[t * 2 + 1];
  const int s0 = pairslot[t * 2], s1 = pairslot[t * 2 + 1];
  const short4v a = ((const short4v*)(ybuf + (size_t)s0 * D_DIM))[tid];
  const short4v b = ((const short4v*)(ybuf + (size_t)s1 * D_DIM))[tid];
  float4 o;
  o.x = w0 * bf2f(a.x) + w1 * bf2f(b.x);
  o.y = w0 * bf2f(a.y) + w1 * bf2f(b.y);
  o.z = w0 * bf2f(a.z) + w1 * bf2f(b.z);
  o.w = w0 * bf2f(a.w) + w1 * bf2f(b.w);
  ((float4*)(out + (size_t)t * D_DIM))[tid] = o;
}

// ---------------- launch ----------------------------------------------------
extern "C" void kernel_launch(void* const* d_in, const int* in_sizes, int n_in,
                              void* d_out, int out_size, void* d_ws, size_t ws_size,
                              hipStream_t stream)
{
  const float* X  = (const float*)d_in[0];
  const float* Wg = (const float*)d_in[1];
  const float* bg = (const float*)d_in[2];
  const float* W1 = (const float*)d_in[3];
  const float* b1 = (const float*)d_in[4];
  const float* W2 = (const float*)d_in[5];
  const float* b2 = (const float*)d_in[6];
  float* out = (float*)d_out;

  char* ws = (char*)d_ws;
  size_t off = 0;
  auto alloc = [&](size_t sz) {
    size_t o = off;
    off = (off + sz + 255) & ~(size_t)255;
    return o;
  };
  int*            cnt      = (int*)(ws + alloc(NE * sizeof(int)));
  int*            expoff   = (int*)(ws + alloc(NE * sizeof(int)));
  int*            toff     = (int*)(ws + alloc((NE + 1) * sizeof(int)));
  int*            bucket   = (int*)(ws + alloc((size_t)NE * CAP * sizeof(int)));
  float*          pairw    = (float*)(ws + alloc((size_t)N_TOK * 2 * sizeof(float)));
  int*            pairslot = (int*)(ws + alloc((size_t)N_TOK * 2 * sizeof(int)));
  unsigned short* Xb       = (unsigned short*)(ws + alloc((size_t)N_TOK * D_DIM * 2));
  unsigned short* W1t      = (unsigned short*)(ws + alloc((size_t)NE * D_DIM * F_DIM * 2));
  unsigned short* W2t      = (unsigned short*)(ws + alloc((size_t)NE * D_DIM * F_DIM * 2));
  unsigned short* hmid     = (unsigned short*)(ws + alloc((size_t)(N_TOK * 2 + 256) * F_DIM * 2));
  unsigned short* ybuf     = W1t;   // W1t dead after GEMM1; ybuf written in GEMM2

  hipMemsetAsync(cnt, 0, NE * sizeof(int), stream);

  gate_kernel<<<N_TOK, 256, 0, stream>>>(X, Wg, bg, cnt, bucket, pairw, Xb);
  transpose_both_kernel<<<dim3(64, 16, 2 * NE), 256, 0, stream>>>(W1, W2, W1t, W2t);
  prefix_kernel<<<1, 64, 0, stream>>>(cnt, expoff, toff);
  fillslot_kernel<<<NE, 256, 0, stream>>>(cnt, expoff, bucket, pairslot);

  moe_gemm<1><<<MAXT * (F_DIM / 128), 512, 0, stream>>>(   // 2304 blocks (%8==0)
      Xb, W1t, b1, cnt, expoff, toff, bucket, hmid);
  moe_gemm<2><<<MAXT * (D_DIM / 128), 512, 0, stream>>>(   // 576 blocks (%8==0)
      hmid, W2t, b2, cnt, expoff, toff, bucket, ybuf);
  combine_kernel<<<N_TOK, 256, 0, stream>>>(ybuf, pairw, pairslot, out);
}

// Round 15
// 784.438 us; speedup vs baseline: 1.7738x; 1.0537x over previous
//
#include <hip/hip_runtime.h>
#include <hip/hip_bf16.h>
#include <cstdint>
#include <math.h>

#define N_TOK 8192
#define D_DIM 1024
#define F_DIM 4096
#define NE 8
#define CAP 8192
#define MAXT 72    // max sum_e ceil(cnt_e/256) = 71, padded

typedef __attribute__((ext_vector_type(8))) short short8;
typedef __attribute__((ext_vector_type(4))) short short4v;
typedef __attribute__((ext_vector_type(4))) float f32x4;

__device__ __forceinline__ short f2bf(float f) {
  __bf16 b = (__bf16)f;
  return *(short*)&b;
}
__device__ __forceinline__ float bf2f(short u) {
  union { unsigned int i; float f; } c;
  c.i = ((unsigned int)(unsigned short)u) << 16;
  return c.f;
}
__device__ __forceinline__ void gload(const void* g, void* l) {
  __builtin_amdgcn_global_load_lds(
      (const __attribute__((address_space(1))) uint32_t*)g,
      (__attribute__((address_space(3))) uint32_t*)l, 16, 0, 0);
}

// ---------------- gating + fused X->bf16 ------------------------------------
__global__ __launch_bounds__(256) void gate_kernel(
    const float* __restrict__ X, const float* __restrict__ Wg,
    const float* __restrict__ bg, int* __restrict__ cnt,
    int* __restrict__ bucket, float* __restrict__ pairw,
    unsigned short* __restrict__ Xb)
{
  const int token = blockIdx.x;
  const int tid = threadIdx.x;
  const float4* x4 = (const float4*)(X + (size_t)token * D_DIM);
  const float4* wg4 = (const float4*)Wg;
  float part[NE];
#pragma unroll
  for (int e = 0; e < NE; ++e) part[e] = 0.f;
  const float4 xv = x4[tid];
#pragma unroll
  for (int e = 0; e < NE; ++e) {
    const float4 wv = wg4[e * (D_DIM / 4) + tid];
    part[e] = fmaf(xv.x, wv.x, fmaf(xv.y, wv.y, fmaf(xv.z, wv.z, fmaf(xv.w, wv.w, part[e]))));
  }
  short4v o;
  o.x = f2bf(xv.x); o.y = f2bf(xv.y); o.z = f2bf(xv.z); o.w = f2bf(xv.w);
  ((short4v*)(Xb + (size_t)token * D_DIM))[tid] = o;

#pragma unroll
  for (int e = 0; e < NE; ++e) {
#pragma unroll
    for (int off = 32; off > 0; off >>= 1) part[e] += __shfl_down(part[e], off);
  }
  __shared__ float wsum[4][NE];
  const int wave = tid >> 6;
  if ((tid & 63) == 0) {
#pragma unroll
    for (int e = 0; e < NE; ++e) wsum[wave][e] = part[e];
  }
  __syncthreads();
  if (tid == 0) {
    float lg[NE];
#pragma unroll
    for (int e = 0; e < NE; ++e)
      lg[e] = wsum[0][e] + wsum[1][e] + wsum[2][e] + wsum[3][e] + bg[e];
    int e0 = 0;
#pragma unroll
    for (int e = 1; e < NE; ++e) if (lg[e] > lg[e0]) e0 = e;     // jax tie-break: lower idx
    int e1 = (e0 == 0) ? 1 : 0;
#pragma unroll
    for (int e = 0; e < NE; ++e) if (e != e0 && lg[e] > lg[e1]) e1 = e;
    float p1 = expf(lg[e1] - lg[e0]);            // p0 = 1; softmax denom cancels
    float inv = 1.f / (1.f + p1);
    pairw[token * 2]     = inv;
    pairw[token * 2 + 1] = p1 * inv;
    int pos0 = atomicAdd(&cnt[e0], 1);
    bucket[e0 * CAP + pos0] = token * 2;
    int pos1 = atomicAdd(&cnt[e1], 1);
    bucket[e1 * CAP + pos1] = token * 2 + 1;
  }
}

// ---------------- prefix sums (row offsets + 256-row tile offsets) ----------
__global__ void prefix_kernel(const int* __restrict__ cnt,
                              int* __restrict__ expoff, int* __restrict__ toff)
{
  if (threadIdx.x == 0 && blockIdx.x == 0) {
    int s = 0, t = 0;
#pragma unroll
    for (int e = 0; e < NE; ++e) {
      expoff[e] = s;
      toff[e] = t;
      s += cnt[e];
      t += (cnt[e] + 255) >> 8;
    }
    toff[NE] = t;
  }
}

// ---------------- inverse map: pair -> slot ---------------------------------
__global__ __launch_bounds__(256) void fillslot_kernel(
    const int* __restrict__ cnt, const int* __restrict__ expoff,
    const int* __restrict__ bucket, int* __restrict__ pairslot)
{
  const int e = blockIdx.x;
  const int n = cnt[e], off = expoff[e];
  for (int p = threadIdx.x; p < n; p += 256)
    pairslot[bucket[e * CAP + p]] = off + p;
}

// ---------------- both weight transposes in ONE launch ----------------------
__global__ __launch_bounds__(256) void transpose_both_kernel(
    const float* __restrict__ W1, const float* __restrict__ W2,
    unsigned short* __restrict__ W1t, unsigned short* __restrict__ W2t)
{
  __shared__ float tileT[64][68];
  const int z = blockIdx.z;
  const bool is1 = (z < NE);
  const int ez = is1 ? z : z - NE;
  const int R = is1 ? D_DIM : F_DIM;
  const int C = is1 ? F_DIM : D_DIM;
  const float* src = (is1 ? W1 : W2) + (size_t)ez * D_DIM * F_DIM;
  unsigned short* dst = (is1 ? W1t : W2t) + (size_t)ez * D_DIM * F_DIM;
  const int c0 = (is1 ? blockIdx.x : blockIdx.y) * 64;
  const int r0 = (is1 ? blockIdx.y : blockIdx.x) * 64;
  const int tid = threadIdx.x;
  const int cx = tid & 15;
  const int ry = tid >> 4;
#pragma unroll
  for (int i = 0; i < 4; ++i) {
    const int row = ry + i * 16;
    const float4 v = *(const float4*)(src + (size_t)(r0 + row) * C + c0 + cx * 4);
    tileT[cx * 4 + 0][row] = v.x;
    tileT[cx * 4 + 1][row] = v.y;
    tileT[cx * 4 + 2][row] = v.z;
    tileT[cx * 4 + 3][row] = v.w;
  }
  __syncthreads();
#pragma unroll
  for (int i = 0; i < 4; ++i) {
    const int cc = ry + i * 16;
    const float4 v = *(const float4*)(&tileT[cc][cx * 4]);
    short4v o;
    o.x = f2bf(v.x); o.y = f2bf(v.y); o.z = f2bf(v.z); o.w = f2bf(v.w);
    *(short4v*)(dst + (size_t)(c0 + cc) * R + r0 + cx * 4) = o;
  }
}

// ---------------- grouped expert GEMM: 256x256, K=32 halves, ring-4 ---------
// 512 threads, 8 waves (2M x 4N), wave = 128x64, acc[8][4]. LDS: A/B halves =
// 256 rows x 64 B = 16 KB each, ring-4 (128 KB total + rowpair). 64-B-row
// swizzle g(r) = (r>>1)&3 (R12-measured 0 conflicts; 2 lanes/bank).
// Per half H: vmcnt(8) + barrier -> ds_read af[8],bfr[4] -> stage half H+3
// (4 gloads/wave) -> lgkmcnt(0)+sched_barrier -> setprio + 32 MFMA.
// Flight: halves H+1,H+2 always in flight (8 insts/wave) -- never drains.
// WAR: slot (H+3)&3 = (H-1)&3; H-1's reads completed before H's top barrier.
// LAYER 1: hmid[slot] = gelu(Xb @ W1t + b1), K=1024.
// LAYER 2 (split-K=2): ybufA/B[slot] = hmid @ W2t (+b2 in split 0), K=2048 ea.
template<int LAYER>
__global__ __launch_bounds__(512) void moe_gemm(
    const unsigned short* __restrict__ Abase,
    const unsigned short* __restrict__ Bt,
    const float* __restrict__ bias,
    const int* __restrict__ cnt,
    const int* __restrict__ expoff,
    const int* __restrict__ toff,
    const int* __restrict__ bucket,
    unsigned short* __restrict__ OutA,
    unsigned short* __restrict__ OutB)
{
  constexpr int BM = 256, BN = 256;
  constexpr int KDIM = (LAYER == 1) ? D_DIM : F_DIM;
  constexpr int NDIM = (LAYER == 1) ? F_DIM : D_DIM;
  constexpr int KSPAN = (LAYER == 1) ? KDIM : (KDIM / 2);  // per-block K range
  constexpr int HALVES = KSPAN / 32;                       // 32 or 64

  const int q = gridDim.x >> 3;
  const int g = (blockIdx.x & 7) * q + (blockIdx.x >> 3);
  const int cc = g / MAXT;                 // L1: ntile; L2: (ntile<<1)|split
  const int mt = g % MAXT;
  if (mt >= toff[NE]) return;
  int e = 0;
  while (mt >= toff[e + 1]) ++e;
  const int mtile = mt - toff[e];
  const int cnt_e = cnt[e];
  const int eoff = expoff[e];
  const int ntile = (LAYER == 1) ? cc : (cc >> 1);
  const int split = (LAYER == 1) ? 0 : (cc & 1);
  const int kbase = split * KSPAN;

  __shared__ __align__(16) char Alds[4 * 16384];   // 64 KiB ring-4
  __shared__ __align__(16) char Blds[4 * 16384];   // 64 KiB ring-4
  __shared__ int rowpair[BM];

  const int tid = threadIdx.x;
  const int lane = tid & 63;
  const int l15 = lane & 15, lhi = lane >> 4;
  const int wid = tid >> 6;
  const int uw = __builtin_amdgcn_readfirstlane(wid);
  const int wm = wid >> 2, wn = wid & 3;           // 2M x 4N

  if (LAYER == 1) {
    if (tid < BM) {
      int pos = mtile * BM + tid;
      rowpair[tid] = (pos < cnt_e) ? bucket[e * CAP + pos] : -1;
    }
    __syncthreads();
  }

  // staging: half = 1024 chunks of 16 B; thread owns ci = i*512+tid (i=0,1);
  // r = ci>>2, c = ci&3; source chunk sc = c ^ ((r>>1)&3) (inverse swizzle)
  // so linear DMA dest (ci*16 = i*8192 + uw*1024 + lane*16) == read image.
  const unsigned short* a_src[2];
  const unsigned short* b_src[2];
#pragma unroll
  for (int i = 0; i < 2; ++i) {
    int ci = i * 512 + tid;
    int r = ci >> 2, c = ci & 3;
    int sc = c ^ ((r >> 1) & 3);
    size_t arow;
    if (LAYER == 1) {
      int pair = rowpair[r];
      arow = (pair < 0) ? 0 : (size_t)(pair >> 1);
    } else {
      arow = (size_t)(eoff + mtile * BM + r);      // contiguous slot rows
    }
    a_src[i] = Abase + arow * KDIM + kbase + sc * 8;
    b_src[i] = Bt + (size_t)e * NDIM * KDIM +
               (size_t)(ntile * BN + r) * KDIM + kbase + sc * 8;
  }

  auto stage = [&](int h) {
    const int s = h & 3;
#pragma unroll
    for (int i = 0; i < 2; ++i)
      gload(a_src[i] + h * 32, &Alds[0] + s * 16384 + i * 8192 + uw * 1024);
#pragma unroll
    for (int i = 0; i < 2; ++i)
      gload(b_src[i] + h * 32, &Blds[0] + s * 16384 + i * 8192 + uw * 1024);
  };

  f32x4 acc[8][4];
#pragma unroll
  for (int m = 0; m < 8; ++m)
#pragma unroll
    for (int n = 0; n < 4; ++n) acc[m][n] = (f32x4){0.f, 0.f, 0.f, 0.f};

  stage(0); stage(1); stage(2);            // 12 insts/wave outstanding

  for (int H = 0; H < HALVES; ++H) {
    if (H + 2 < HALVES)      asm volatile("s_waitcnt vmcnt(8)" ::: "memory");
    else if (H + 1 < HALVES) asm volatile("s_waitcnt vmcnt(4)" ::: "memory");
    else                     asm volatile("s_waitcnt vmcnt(0)" ::: "memory");
    __builtin_amdgcn_sched_barrier(0);
    __builtin_amdgcn_s_barrier();

    const char* aSlot = &Alds[0] + (H & 3) * 16384;
    const char* bSlot = &Blds[0] + (H & 3) * 16384;
    short8 bfr[4], af[8];
#pragma unroll
    for (int n = 0; n < 4; ++n) {
      const int row = wn * 64 + n * 16 + l15;
      bfr[n] = *(const short8*)(bSlot + row * 64 + ((lhi ^ ((row >> 1) & 3)) << 4));
    }
#pragma unroll
    for (int m = 0; m < 8; ++m) {
      const int row = wm * 128 + m * 16 + l15;
      af[m] = *(const short8*)(aSlot + row * 64 + ((lhi ^ ((row >> 1) & 3)) << 4));
    }
    if (H + 3 < HALVES) stage(H + 3);      // refills slot (H-1)&3
    asm volatile("s_waitcnt lgkmcnt(0)" ::: "memory");
    __builtin_amdgcn_sched_barrier(0);
    __builtin_amdgcn_s_setprio(1);
#pragma unroll
    for (int m = 0; m < 8; ++m)
#pragma unroll
      for (int n = 0; n < 4; ++n)
        acc[m][n] = __builtin_amdgcn_mfma_f32_16x16x32_bf16(af[m], bfr[n], acc[m][n], 0, 0, 0);
    __builtin_amdgcn_s_setprio(0);
  }

  // epilogue: C/D layout col = lane&15, row = (lane>>4)*4 + j
#pragma unroll
  for (int m = 0; m < 8; ++m) {
#pragma unroll
    for (int j = 0; j < 4; ++j) {
      const int row = wm * 128 + m * 16 + lhi * 4 + j;
      if (mtile * BM + row >= cnt_e) continue;
      const size_t slot = (size_t)(eoff + mtile * BM + row);
#pragma unroll
      for (int n = 0; n < 4; ++n) {
        const int col = ntile * BN + wn * 64 + n * 16 + l15;
        if (LAYER == 1) {
          float val = acc[m][n][j] + bias[e * NDIM + col];
          float gl = 0.5f * val * (1.f + erff(val * 0.70710678118654752f));
          OutA[slot * F_DIM + col] = (unsigned short)f2bf(gl);
        } else {
          float val = acc[m][n][j] + (split == 0 ? bias[e * NDIM + col] : 0.f);
          unsigned short* dst = (split == 0) ? OutA : OutB;
          dst[slot * D_DIM + col] = (unsigned short)f2bf(val);
        }
      }
    }
  }
}

// ---------------- combine: out[t] = w0*(yA+yB)[s0] + w1*(yA+yB)[s1] ---------
__global__ __launch_bounds__(256) void combine_kernel(
    const unsigned short* __restrict__ ybufA, const unsigned short* __restrict__ ybufB,
    const float* __restrict__ pairw, const int* __restrict__ pairslot,
    float* __restrict__ out)
{
  const int t = blockIdx.x;
  const int tid = threadIdx.x;
  const float w0 = pairw[t * 2], w1 = pairw[t * 2 + 1];
  const int s0 = pairslot[t * 2], s1 = pairslot[t * 2 + 1];
  const short4v a0 = ((const short4v*)(ybufA + (size_t)s0 * D_DIM))[tid];
  const short4v b0 = ((const short4v*)(ybufB + (size_t)s0 * D_DIM))[tid];
  const short4v a1 = ((const short4v*)(ybufA + (size_t)s1 * D_DIM))[tid];
  const short4v b1 = ((const short4v*)(ybufB + (size_t)s1 * D_DIM))[tid];
  float4 o;
  o.x = w0 * (bf2f(a0.x) + bf2f(b0.x)) + w1 * (bf2f(a1.x) + bf2f(b1.x));
  o.y = w0 * (bf2f(a0.y) + bf2f(b0.y)) + w1 * (bf2f(a1.y) + bf2f(b1.y));
  o.z = w0 * (bf2f(a0.z) + bf2f(b0.z)) + w1 * (bf2f(a1.z) + bf2f(b1.z));
  o.w = w0 * (bf2f(a0.w) + bf2f(b0.w)) + w1 * (bf2f(a1.w) + bf2f(b1.w));
  ((float4*)(out + (size_t)t * D_DIM))[tid] = o;
}

// ---------------- launch ----------------------------------------------------
extern "C" void kernel_launch(void* const* d_in, const int* in_sizes, int n_in,
                              void* d_out, int out_size, void* d_ws, size_t ws_size,
                              hipStream_t stream)
{
  const float* X  = (const float*)d_in[0];
  const float* Wg = (const float*)d_in[1];
  const float* bg = (const float*)d_in[2];
  const float* W1 = (const float*)d_in[3];
  const float* b1 = (const float*)d_in[4];
  const float* W2 = (const float*)d_in[5];
  const float* b2 = (const float*)d_in[6];
  float* out = (float*)d_out;

  char* ws = (char*)d_ws;
  size_t off = 0;
  auto alloc = [&](size_t sz) {
    size_t o = off;
    off = (off + sz + 255) & ~(size_t)255;
    return o;
  };
  int*            cnt      = (int*)(ws + alloc(NE * sizeof(int)));
  int*            expoff   = (int*)(ws + alloc(NE * sizeof(int)));
  int*            toff     = (int*)(ws + alloc((NE + 1) * sizeof(int)));
  int*            bucket   = (int*)(ws + alloc((size_t)NE * CAP * sizeof(int)));
  float*          pairw    = (float*)(ws + alloc((size_t)N_TOK * 2 * sizeof(float)));
  int*            pairslot = (int*)(ws + alloc((size_t)N_TOK * 2 * sizeof(int)));
  unsigned short* Xb       = (unsigned short*)(ws + alloc((size_t)N_TOK * D_DIM * 2));
  unsigned short* W1t      = (unsigned short*)(ws + alloc((size_t)NE * D_DIM * F_DIM * 2));
  unsigned short* W2t      = (unsigned short*)(ws + alloc((size_t)NE * D_DIM * F_DIM * 2));
  unsigned short* hmid     = (unsigned short*)(ws + alloc((size_t)(N_TOK * 2 + 256) * F_DIM * 2));
  unsigned short* ybufB    = (unsigned short*)(ws + alloc((size_t)(N_TOK * 2 + 256) * D_DIM * 2));
  unsigned short* ybufA    = W1t;   // W1t dead after GEMM1

  hipMemsetAsync(cnt, 0, NE * sizeof(int), stream);

  gate_kernel<<<N_TOK, 256, 0, stream>>>(X, Wg, bg, cnt, bucket, pairw, Xb);
  transpose_both_kernel<<<dim3(64, 16, 2 * NE), 256, 0, stream>>>(W1, W2, W1t, W2t);
  prefix_kernel<<<1, 64, 0, stream>>>(cnt, expoff, toff);
  fillslot_kernel<<<NE, 256, 0, stream>>>(cnt, expoff, bucket, pairslot);

  moe_gemm<1><<<MAXT * (F_DIM / 256), 512, 0, stream>>>(   // 1152 blocks (%8==0)
      Xb, W1t, b1, cnt, expoff, toff, bucket, hmid, nullptr);
  moe_gemm<2><<<MAXT * (D_DIM / 256) * 2, 512, 0, stream>>>( // 576 blocks (%8==0)
      hmid, W2t, b2, cnt, expoff, toff, bucket, ybufA, ybufB);
  combine_kernel<<<N_TOK, 256, 0, stream>>>(ybufA, ybufB, pairw, pairslot, out);
}